// Round 4
// baseline (200.751 us; speedup 1.0000x reference)
//
#include <hip/hip_runtime.h>
#include <math.h>

#define N 3072
#define FEAT 128
#define NE 24576
#define NP (2 * NE)        // directed pair slots
#define DOUT_ZB 9606       // d_out zero blocks (4096 B each): 9606*4096 = out_size*4
#define WS_ZB 297          // ws zero region blocks: 297*4096 = mask+rcnt+pcnt+notsing
#define RESCAP 4096        // residual-edge LDS capacity
#define RSTRIDE 64         // reverse-CSR row stride (max in-degree guard)
#define PSTRIDE 64         // per-node pair-slot row stride

// Wave-aggregated atomic add: group lanes by key, one atomicAdd per distinct
// key per wave. All 64 lanes must reach this call (use `valid`, not early-return).
__device__ __forceinline__ void wave_agg_add(bool valid, int key, float val,
                                             float* base, int stride, int off) {
    int lane = threadIdx.x & 63;
    unsigned long long active = __ballot(valid ? 1 : 0);
    while (active) {
        int leader = __ffsll(active) - 1;
        int lkey = __shfl(key, leader);
        bool mine = valid && (key == lkey);
        unsigned long long grp = __ballot(mine ? 1 : 0);
        float v = mine ? val : 0.0f;
        #pragma unroll
        for (int o = 32; o; o >>= 1) v += __shfl_xor(v, o);
        if (lane == leader)
            atomicAdd(&base[(size_t)lkey * stride + off], v);
        active &= ~grp;
    }
}

// blocks [0,N): a[i]=x[i].w[0:128], c[i]=x[i].w[128:256]
// blocks [N,N+DOUT_ZB): zero d_out (4 KB/block)
// blocks [N+DOUT_ZB, +WS_ZB): zero ws region [mask|rcnt|pcnt|notsing]
__global__ void k_dots_zero(const float* __restrict__ x, const float* __restrict__ w,
                            float* __restrict__ a, float* __restrict__ c,
                            float4* __restrict__ zout, float4* __restrict__ zws) {
    int b = blockIdx.x;
    int l = threadIdx.x;
    if (b < N) {
        const float* xi = x + b * FEAT;
        float pa = xi[l] * w[l] + xi[l + 64] * w[l + 64];
        float pc = xi[l] * w[FEAT + l] + xi[l + 64] * w[FEAT + l + 64];
        for (int off = 32; off; off >>= 1) {
            pa += __shfl_down(pa, off);
            pc += __shfl_down(pc, off);
        }
        if (l == 0) { a[b] = pa; c[b] = pc; }
    } else {
        float4 z = {0.f, 0.f, 0.f, 0.f};
        float4* dst;
        size_t base;
        if (b < N + DOUT_ZB) { base = (size_t)(b - N) * 256; dst = zout; }
        else                 { base = (size_t)(b - N - DOUT_ZB) * 256; dst = zws; }
        dst[base + l]       = z;
        dst[base + 64 + l]  = z;
        dst[base + 128 + l] = z;
        dst[base + 192 + l] = z;
    }
}

// pack edges u|v<<12|fu<<24|fv<<25, mark not-single nodes, build reverse CSR:
// directed contraction edge p->q (label flows q->p) => rtab row q contains p.
__global__ void k_edgeflags(const int* __restrict__ ei, const float* __restrict__ a,
                            const float* __restrict__ c, const float* __restrict__ bb,
                            unsigned* __restrict__ ep, int* __restrict__ notsingle,
                            int* __restrict__ rcnt, unsigned short* __restrict__ rtab) {
    int t = blockIdx.x * blockDim.x + threadIdx.x;
    if (t >= NE) return;
    int u = ei[t], v = ei[NE + t];
    unsigned wpk = (unsigned)u | ((unsigned)v << 12);
    if (u != v) {
        float b = bb[0];
        unsigned fu = (a[u] + c[v] + b > 0.f) ? 1u : 0u;  // A_c[u,v]=1: lab[u]<-lab[v]
        unsigned fv = (a[v] + c[u] + b > 0.f) ? 1u : 0u;  // A_c[v,u]=1: lab[v]<-lab[u]
        wpk |= (fu << 24) | (fv << 25);
        if (fu | fv) { notsingle[u] = 1; notsingle[v] = 1; }
        if (fu) {
            int pos = atomicAdd(&rcnt[v], 1);
            if (pos < RSTRIDE) rtab[v * RSTRIDE + pos] = (unsigned short)u;
        }
        if (fv) {
            int pos = atomicAdd(&rcnt[u], 1);
            if (pos < RSTRIDE) rtab[u * RSTRIDE + pos] = (unsigned short)v;
        }
    }
    ep[t] = wpk;
}

// single workgroup: reverse-BFS from node 0 (labels its whole reach 0),
// residual fixpoint on the (tiny) unreached subgraph, then rank + cluster.
__global__ void __launch_bounds__(1024)
k_prop_rank(const unsigned* __restrict__ ep, const int* __restrict__ rcnt,
            const unsigned short* __restrict__ rtab,
            int* __restrict__ cluster, float* __restrict__ out_cluster) {
    __shared__ int lab[N];
    __shared__ unsigned short queue[N];
    __shared__ unsigned res[RESCAP];
    __shared__ int ssum[1024];
    __shared__ unsigned short rk[N];
    __shared__ int qs, qe, qt, rescnt, flag;
    int t = threadIdx.x;
    for (int i = t; i < N; i += 1024) lab[i] = i;
    if (t == 0) { qs = 0; qe = 1; qt = 1; queue[0] = 0; rescnt = 0; }
    __syncthreads();
    // level-synchronous BFS over reverse graph from node 0
    while (qs < qe) {
        for (int i = qs + t; i < qe; i += 1024) {
            int z = queue[i];
            int cnt = rcnt[z]; if (cnt > RSTRIDE) cnt = RSTRIDE;
            const unsigned short* row = rtab + z * RSTRIDE;
            for (int j = 0; j < cnt; ++j) {
                int p = row[j];
                if (lab[p] != 0) {
                    int old = atomicMin(&lab[p], 0);
                    if (old != 0) {
                        int pos = atomicAdd(&qt, 1);
                        queue[pos] = (unsigned short)p;
                    }
                }
            }
        }
        __syncthreads();
        if (t == 0) { qs = qe; qe = qt; }
        __syncthreads();
    }
    // compact residual directed edges (source not labeled 0). The unreached
    // set is closed under out-edges, so the residue is self-contained.
    for (int e = t; e < NE; e += 1024) {
        unsigned wpk = ep[e];
        int u = wpk & 0xFFF, v = (wpk >> 12) & 0xFFF;
        if ((wpk & (1u << 24)) && lab[u] != 0) {
            int pos = atomicAdd(&rescnt, 1);
            if (pos < RESCAP) res[pos] = (unsigned)u | ((unsigned)v << 12);
        }
        if ((wpk & (1u << 25)) && lab[v] != 0) {
            int pos = atomicAdd(&rescnt, 1);
            if (pos < RESCAP) res[pos] = (unsigned)v | ((unsigned)u << 12);
        }
    }
    __syncthreads();
    int nres = rescnt;
    bool ovf = (nres > RESCAP);
    // fixpoint on residual subgraph (fallback to full edge list on overflow)
    for (;;) {
        __syncthreads();
        if (t == 0) flag = 0;
        __syncthreads();
        if (!ovf) {
            for (int k = t; k < nres; k += 1024) {
                unsigned w2 = res[k];
                int u = w2 & 0xFFF, v = (w2 >> 12) & 0xFFF;
                int lv = lab[v];
                if (lv < lab[u]) { atomicMin(&lab[u], lv); flag = 1; }
            }
        } else {
            for (int e = t; e < NE; e += 1024) {
                unsigned wpk = ep[e];
                int u = wpk & 0xFFF, v = (wpk >> 12) & 0xFFF;
                if (wpk & (1u << 24)) {
                    int lv = lab[v];
                    if (lv < lab[u]) { atomicMin(&lab[u], lv); flag = 1; }
                }
                if (wpk & (1u << 25)) {
                    int lu = lab[u];
                    if (lu < lab[v]) { atomicMin(&lab[v], lu); flag = 1; }
                }
            }
        }
        for (int i = t; i < N; i += 1024) {
            int m = lab[i];
            int mm = lab[m];
            while (mm < m) { m = mm; mm = lab[m]; }
            if (m < lab[i]) { atomicMin(&lab[i], m); flag = 1; }
        }
        __syncthreads();
        if (!flag) break;
    }
    // rank roots: cumsum(lab[i]==i)-1; cluster[j] = rank[lab[j]]
    int i0 = 3 * t;
    int r0 = (lab[i0] == i0);
    int r1 = (lab[i0 + 1] == i0 + 1);
    int r2 = (lab[i0 + 2] == i0 + 2);
    int s = r0 + r1 + r2;
    ssum[t] = s;
    __syncthreads();
    for (int off = 1; off < 1024; off <<= 1) {
        int val = (t >= off) ? ssum[t - off] : 0;
        __syncthreads();
        ssum[t] += val;
        __syncthreads();
    }
    int run = ssum[t] - s;
    run += r0; rk[i0]     = (unsigned short)(run - 1);
    run += r1; rk[i0 + 1] = (unsigned short)(run - 1);
    run += r2; rk[i0 + 2] = (unsigned short)(run - 1);
    __syncthreads();
    for (int j = t; j < N; j += 1024) {
        int cl = rk[lab[j]];
        cluster[j] = cl;
        out_cluster[j] = (float)cl;
    }
}

// One lane per directed pair slot: dedup via bitmask, append (p, e) into q's
// slot row for the gather, wave-aggregated count into A_new.
__global__ void k_pairs(const unsigned* __restrict__ ep, const float* __restrict__ a,
                        const float* __restrict__ c, const float* __restrict__ bb,
                        const int* __restrict__ cluster, unsigned* __restrict__ mask,
                        int* __restrict__ pcnt, unsigned long long* __restrict__ ptab,
                        float* __restrict__ Anew) {
    int t = blockIdx.x * blockDim.x + threadIdx.x;   // exactly NP threads
    int dir = (t >= NE) ? 1 : 0;
    int idx = dir ? t - NE : t;
    unsigned wpk = ep[idx];
    int u = wpk & 0xFFF, v = (wpk >> 12) & 0xFFF;
    int p = dir ? v : u;
    int q = dir ? u : v;
    int o = 0;
    if (u != v) {
        unsigned pos = (unsigned)p * N + (unsigned)q;
        unsigned bit = 1u << (pos & 31u);
        unsigned old = atomicOr(&mask[pos >> 5], bit);
        o = !(old & bit);
    }
    int key = 0;
    if (o) {
        float e = tanhf(a[p] + c[q] + bb[0]);
        key = cluster[p] * N + cluster[q];
        int sl = atomicAdd(&pcnt[q], 1);
        if (sl < PSTRIDE)
            ptab[(size_t)q * PSTRIDE + sl] =
                ((unsigned long long)__float_as_uint(e) << 32) | (unsigned)p;
    }
    wave_agg_add(o != 0, key, 1.0f, Anew, 1, 0);
}

// one wave per node q: y[q] = sum_{(p,q) distinct} e*x[p] (+ x[q] if single).
// Register accumulation, plain stores — no atomics, no y memset needed.
__global__ void k_gather(const float* __restrict__ x, const int* __restrict__ pcnt,
                         const unsigned long long* __restrict__ ptab,
                         const int* __restrict__ notsingle, float* __restrict__ y) {
    int wid = (blockIdx.x * blockDim.x + threadIdx.x) >> 6;
    int lane = threadIdx.x & 63;
    int cnt = pcnt[wid]; if (cnt > PSTRIDE) cnt = PSTRIDE;
    const unsigned long long* row = ptab + (size_t)wid * PSTRIDE;
    float acc0 = 0.f, acc1 = 0.f;
    for (int j = 0; j < cnt; ++j) {
        unsigned long long s = row[j];
        int p = (int)(s & 0xFFFFFFFFu);
        float e = __uint_as_float((unsigned)(s >> 32));
        const float* xp = x + p * FEAT;
        acc0 += e * xp[lane];
        acc1 += e * xp[lane + 64];
    }
    if (!notsingle[wid]) {
        const float* xq = x + wid * FEAT;
        acc0 += xq[lane];
        acc1 += xq[lane + 64];
    }
    float* yq = y + wid * FEAT;
    yq[lane] = acc0;
    yq[lane + 64] = acc1;
}

// waves [0,6144): X_new[cluster[q]][f] += y[q][f], wave-aggregated by cluster.
// waves [6144,6192): zero A_new diagonal.
__global__ void k_reduce(const float* __restrict__ y, const int* __restrict__ cluster,
                         float* __restrict__ Xnew, float* __restrict__ Anew) {
    int wid = (blockIdx.x * blockDim.x + threadIdx.x) >> 6;
    int lane = threadIdx.x & 63;
    if (wid < 6144) {
        int f = wid & (FEAT - 1);
        int chunk = wid >> 7;
        int q = chunk * 64 + lane;
        float val = y[q * FEAT + f];
        int key = cluster[q];
        wave_agg_add(true, key, val, Xnew, FEAT, f);
    } else {
        int i = (wid - 6144) * 64 + lane;
        Anew[(size_t)i * N + i] = 0.0f;
    }
}

extern "C" void kernel_launch(void* const* d_in, const int* in_sizes, int n_in,
                              void* d_out, int out_size, void* d_ws, size_t ws_size,
                              hipStream_t stream) {
    const float* x  = (const float*)d_in[0];
    const int*   ei = (const int*)d_in[1];
    const float* w  = (const float*)d_in[3];
    const float* bb = (const float*)d_in[4];

    // workspace layout — zeroed region FIRST: [mask | rcnt | pcnt | notsing]
    char* ws = (char*)d_ws;
    size_t off = 0;
    unsigned* mask = (unsigned*)(ws + off); off += (size_t)N * N / 8;   // 1,179,648
    int* rcnt      = (int*)(ws + off);      off += (size_t)N * 4;       //    12,288
    int* pcnt      = (int*)(ws + off);      off += (size_t)N * 4;       //    12,288
    int* notsing   = (int*)(ws + off);      off += (size_t)N * 4;       //    12,288
    // zero region total = 1,216,512 B = WS_ZB * 4096
    float* a       = (float*)(ws + off);    off += (size_t)N * 4;
    float* c       = (float*)(ws + off);    off += (size_t)N * 4;
    int* cluster   = (int*)(ws + off);      off += (size_t)N * 4;
    unsigned* ep   = (unsigned*)(ws + off); off += (size_t)NE * 4;
    unsigned short* rtab = (unsigned short*)(ws + off); off += (size_t)N * RSTRIDE * 2;
    float* y       = (float*)(ws + off);    off += (size_t)N * FEAT * 4;
    unsigned long long* ptab = (unsigned long long*)(ws + off); off += (size_t)N * PSTRIDE * 8;

    // output layout (all float32)
    float* Xnew        = (float*)d_out;                 // N*FEAT
    float* Anew        = Xnew + (size_t)N * FEAT;       // N*N
    float* out_cluster = Anew + (size_t)N * N + N;      // after new_batch (zeros)

    k_dots_zero<<<N + DOUT_ZB + WS_ZB, 64, 0, stream>>>(x, w, a, c,
                                                        (float4*)d_out, (float4*)ws);
    k_edgeflags<<<NE / 256, 256, 0, stream>>>(ei, a, c, bb, ep, notsing, rcnt, rtab);
    k_prop_rank<<<1, 1024, 0, stream>>>(ep, rcnt, rtab, cluster, out_cluster);
    k_pairs<<<NP / 256, 256, 0, stream>>>(ep, a, c, bb, cluster, mask, pcnt, ptab, Anew);
    k_gather<<<(N * 64) / 256, 256, 0, stream>>>(x, pcnt, ptab, notsing, y);
    k_reduce<<<(6192 * 64) / 256, 256, 0, stream>>>(y, cluster, Xnew, Anew);
}

// Round 6
// 140.110 us; speedup vs baseline: 1.4328x; 1.4328x over previous
//
#include <hip/hip_runtime.h>
#include <math.h>

#define N 3072
#define FEAT 128
#define NE 24576
#define NP (2 * NE)        // directed pair slots
#define DOUT_ZB 9606       // d_out zero blocks: 9606*4096 B = out_size*4
#define WS_ZB 294          // ws zero region: [mask|pcnt|notsing] = 294*4096 B
#define PSTRIDE 64         // per-node pair-slot row stride
#define EPT 24             // edges per prop thread (NE/1024)

// Wave-aggregated atomic add: group lanes by key, one atomicAdd per distinct
// key per wave. All 64 lanes must reach this call (use `valid`, not early-return).
__device__ __forceinline__ void wave_agg_add(bool valid, int key, float val,
                                             float* base, int stride, int off) {
    int lane = threadIdx.x & 63;
    unsigned long long active = __ballot(valid ? 1 : 0);
    while (active) {
        int leader = __ffsll(active) - 1;
        int lkey = __shfl(key, leader);
        bool mine = valid && (key == lkey);
        unsigned long long grp = __ballot(mine ? 1 : 0);
        float v = mine ? val : 0.0f;
        #pragma unroll
        for (int o = 32; o; o >>= 1) v += __shfl_xor(v, o);
        if (lane == leader)
            atomicAdd(&base[(size_t)lkey * stride + off], v);
        active &= ~grp;
    }
}

// blocks [0,N): a[i]=x[i].w[0:128], c[i]=x[i].w[128:256]
// blocks [N,N+DOUT_ZB): zero d_out; blocks [N+DOUT_ZB,+WS_ZB): zero ws region
__global__ void k_dots_zero(const float* __restrict__ x, const float* __restrict__ w,
                            float* __restrict__ a, float* __restrict__ c,
                            float4* __restrict__ zout, float4* __restrict__ zws) {
    int b = blockIdx.x;
    int l = threadIdx.x;
    if (b < N) {
        const float* xi = x + b * FEAT;
        float pa = xi[l] * w[l] + xi[l + 64] * w[l + 64];
        float pc = xi[l] * w[FEAT + l] + xi[l + 64] * w[FEAT + l + 64];
        for (int off = 32; off; off >>= 1) {
            pa += __shfl_down(pa, off);
            pc += __shfl_down(pc, off);
        }
        if (l == 0) { a[b] = pa; c[b] = pc; }
    } else {
        float4 z = {0.f, 0.f, 0.f, 0.f};
        float4* dst;
        size_t base;
        if (b < N + DOUT_ZB) { base = (size_t)(b - N) * 256; dst = zout; }
        else                 { base = (size_t)(b - N - DOUT_ZB) * 256; dst = zws; }
        dst[base + l]       = z;
        dst[base + 64 + l]  = z;
        dst[base + 128 + l] = z;
        dst[base + 192 + l] = z;
    }
}

// Fused edge kernel: pack u|v<<12|fu<<24|fv<<25|own0<<26|own1<<27, mark
// not-single nodes, dedup both directed pairs via bitmask, push (e,p) into q's
// gather row.
__global__ void k_edge_pairs(const int* __restrict__ ei, const float* __restrict__ a,
                             const float* __restrict__ c, const float* __restrict__ bb,
                             unsigned* __restrict__ ep, int* __restrict__ notsingle,
                             unsigned* __restrict__ mask, int* __restrict__ pcnt,
                             unsigned long long* __restrict__ ptab) {
    int t = blockIdx.x * blockDim.x + threadIdx.x;
    if (t >= NE) return;
    int u = ei[t], v = ei[NE + t];
    unsigned wpk = (unsigned)u | ((unsigned)v << 12);
    if (u != v) {
        float b = bb[0];
        float su = a[u] + c[v] + b;    // score(u->v): S[u,v], A_c[u,v]
        float sv = a[v] + c[u] + b;    // score(v->u): S[v,u], A_c[v,u]
        unsigned fu = (su > 0.f) ? 1u : 0u;
        unsigned fv = (sv > 0.f) ? 1u : 0u;
        wpk |= (fu << 24) | (fv << 25);
        if (fu | fv) { notsingle[u] = 1; notsingle[v] = 1; }
        // dir 0: (p,q) = (u,v)
        unsigned pos = (unsigned)u * N + (unsigned)v;
        unsigned bit = 1u << (pos & 31u);
        unsigned old = atomicOr(&mask[pos >> 5], bit);
        if (!(old & bit)) {
            wpk |= (1u << 26);
            float e = tanhf(su);
            int sl = atomicAdd(&pcnt[v], 1);
            if (sl < PSTRIDE)
                ptab[(size_t)v * PSTRIDE + sl] =
                    ((unsigned long long)__float_as_uint(e) << 32) | (unsigned)u;
        }
        // dir 1: (p,q) = (v,u)
        pos = (unsigned)v * N + (unsigned)u;
        bit = 1u << (pos & 31u);
        old = atomicOr(&mask[pos >> 5], bit);
        if (!(old & bit)) {
            wpk |= (1u << 27);
            float e = tanhf(sv);
            int sl = atomicAdd(&pcnt[u], 1);
            if (sl < PSTRIDE)
                ptab[(size_t)u * PSTRIDE + sl] =
                    ((unsigned long long)__float_as_uint(e) << 32) | (unsigned)v;
        }
    }
    ep[t] = wpk;
}

// block 0: LDS min-label fixpoint (edges register-cached) + rank + cluster.
// blocks 1..192: gather y[q] = sum e*x[p] (+ x[q] if single), one wave per q.
__global__ void __launch_bounds__(1024)
k_prop_gather(const unsigned* __restrict__ ep, const float* __restrict__ x,
              const int* __restrict__ pcnt, const unsigned long long* __restrict__ ptab,
              const int* __restrict__ notsingle, float* __restrict__ y,
              int* __restrict__ cluster, float* __restrict__ out_cluster) {
    __shared__ int lab[N];
    __shared__ int ssum[1024];
    __shared__ unsigned short rk[N];
    __shared__ int flag;
    if (blockIdx.x == 0) {
        int t = threadIdx.x;
        unsigned er[EPT];
        #pragma unroll
        for (int j = 0; j < EPT; ++j) er[j] = ep[t + j * 1024];
        for (int i = t; i < N; i += 1024) lab[i] = i;
        for (;;) {
            __syncthreads();
            if (t == 0) flag = 0;
            __syncthreads();
            #pragma unroll
            for (int j = 0; j < EPT; ++j) {
                unsigned wpk = er[j];
                int u = wpk & 0xFFF, v = (wpk >> 12) & 0xFFF;
                if (wpk & (1u << 24)) {
                    int lv = lab[v];
                    if (lv < lab[u]) { atomicMin(&lab[u], lv); flag = 1; }
                }
                if (wpk & (1u << 25)) {
                    int lu = lab[u];
                    if (lu < lab[v]) { atomicMin(&lab[v], lu); flag = 1; }
                }
            }
            for (int i = t; i < N; i += 1024) {
                int m = lab[i];
                int mm = lab[m];
                while (mm < m) { m = mm; mm = lab[m]; }
                if (m < lab[i]) { atomicMin(&lab[i], m); flag = 1; }
            }
            __syncthreads();
            if (!flag) break;
        }
        // rank roots: cumsum(lab[i]==i)-1; cluster[j] = rank[lab[j]]
        int i0 = 3 * t;
        int r0 = (lab[i0] == i0);
        int r1 = (lab[i0 + 1] == i0 + 1);
        int r2 = (lab[i0 + 2] == i0 + 2);
        int s = r0 + r1 + r2;
        ssum[t] = s;
        __syncthreads();
        for (int off = 1; off < 1024; off <<= 1) {
            int val = (t >= off) ? ssum[t - off] : 0;
            __syncthreads();
            ssum[t] += val;
            __syncthreads();
        }
        int run = ssum[t] - s;
        run += r0; rk[i0]     = (unsigned short)(run - 1);
        run += r1; rk[i0 + 1] = (unsigned short)(run - 1);
        run += r2; rk[i0 + 2] = (unsigned short)(run - 1);
        __syncthreads();
        for (int j = t; j < N; j += 1024) {
            int cl = rk[lab[j]];
            cluster[j] = cl;
            out_cluster[j] = (float)cl;
        }
    } else {
        int q = (blockIdx.x - 1) * 16 + (threadIdx.x >> 6);
        int lane = threadIdx.x & 63;
        int cnt = pcnt[q]; if (cnt > PSTRIDE) cnt = PSTRIDE;
        const unsigned long long* row = ptab + (size_t)q * PSTRIDE;
        float acc0 = 0.f, acc1 = 0.f;
        for (int j = 0; j < cnt; ++j) {
            unsigned long long s = row[j];
            int p = (int)(s & 0xFFFFFFFFu);
            float e = __uint_as_float((unsigned)(s >> 32));
            const float* xp = x + p * FEAT;
            acc0 += e * xp[lane];
            acc1 += e * xp[lane + 64];
        }
        if (!notsingle[q]) {
            const float* xq = x + q * FEAT;
            acc0 += xq[lane];
            acc1 += xq[lane + 64];
        }
        float* yq = y + q * FEAT;
        yq[lane] = acc0;
        yq[lane + 64] = acc1;
    }
}

// waves [0,6144): X_new[cluster[q]][f] += y[q][f] (wave-aggregated).
// waves [6144,6528): A_new counts from ep ownership bits (wave-aggregated).
// Diagonal keys (cu==cv) are SKIPPED — reference zeroes the diagonal after
// the matmul, and d_out is pre-zeroed, so dropping them is exact (and removes
// the hottest same-key atomic stream entirely).
__global__ void k_reduce_anew(const float* __restrict__ y, const int* __restrict__ cluster,
                              const unsigned* __restrict__ ep,
                              float* __restrict__ Xnew, float* __restrict__ Anew) {
    int gid = blockIdx.x * blockDim.x + threadIdx.x;
    int wid = gid >> 6, lane = gid & 63;
    if (wid < 6144) {
        int f = wid & (FEAT - 1);
        int chunk = wid >> 7;
        int q = chunk * 64 + lane;
        wave_agg_add(true, cluster[q], y[q * FEAT + f], Xnew, FEAT, f);
    } else {
        int s = (wid - 6144) * 64 + lane;
        unsigned wpk = ep[s];
        int u = wpk & 0xFFF, v = (wpk >> 12) & 0xFFF;
        int cu = cluster[u], cv = cluster[v];
        bool o0 = ((wpk & (1u << 26)) != 0) && (cu != cv);
        bool o1 = ((wpk & (1u << 27)) != 0) && (cu != cv);
        wave_agg_add(o0, cu * N + cv, 1.0f, Anew, 1, 0);
        wave_agg_add(o1, cv * N + cu, 1.0f, Anew, 1, 0);
    }
}

extern "C" void kernel_launch(void* const* d_in, const int* in_sizes, int n_in,
                              void* d_out, int out_size, void* d_ws, size_t ws_size,
                              hipStream_t stream) {
    const float* x  = (const float*)d_in[0];
    const int*   ei = (const int*)d_in[1];
    const float* w  = (const float*)d_in[3];
    const float* bb = (const float*)d_in[4];

    // workspace layout — zeroed region FIRST: [mask | pcnt | notsing]
    char* ws = (char*)d_ws;
    size_t off = 0;
    unsigned* mask = (unsigned*)(ws + off); off += (size_t)N * N / 8;   // 1,179,648
    int* pcnt      = (int*)(ws + off);      off += (size_t)N * 4;       //    12,288
    int* notsing   = (int*)(ws + off);      off += (size_t)N * 4;       //    12,288
    // zero region total = 1,204,224 B = WS_ZB * 4096
    float* a       = (float*)(ws + off);    off += (size_t)N * 4;
    float* c       = (float*)(ws + off);    off += (size_t)N * 4;
    int* cluster   = (int*)(ws + off);      off += (size_t)N * 4;
    unsigned* ep   = (unsigned*)(ws + off); off += (size_t)NE * 4;
    float* y       = (float*)(ws + off);    off += (size_t)N * FEAT * 4;
    unsigned long long* ptab = (unsigned long long*)(ws + off); off += (size_t)N * PSTRIDE * 8;

    // output layout (all float32)
    float* Xnew        = (float*)d_out;                 // N*FEAT
    float* Anew        = Xnew + (size_t)N * FEAT;       // N*N
    float* out_cluster = Anew + (size_t)N * N + N;      // after new_batch (zeros)

    k_dots_zero<<<N + DOUT_ZB + WS_ZB, 64, 0, stream>>>(x, w, a, c,
                                                        (float4*)d_out, (float4*)ws);
    k_edge_pairs<<<NE / 256, 256, 0, stream>>>(ei, a, c, bb, ep, notsing,
                                               mask, pcnt, ptab);
    k_prop_gather<<<1 + N / 16, 1024, 0, stream>>>(ep, x, pcnt, ptab, notsing, y,
                                                   cluster, out_cluster);
    k_reduce_anew<<<(6528 * 64) / 256, 256, 0, stream>>>(y, cluster, ep, Xnew, Anew);
}